// Round 3
// baseline (296.680 us; speedup 1.0000x reference)
//
#include <hip/hip_runtime.h>
#include <math.h>

#define N_NODES 10000
#define E0      50000
#define E_TOT   60000
#define FIN     128
#define HEADS   8
#define CHN     256
#define HC      2048
#define NC      10
#define NEG     0.2f
#define MAXD    128

// ---------- helpers ----------
__device__ __forceinline__ unsigned f2u(float f){
  unsigned u = __float_as_uint(f);
  return (u & 0x80000000u) ? ~u : (u | 0x80000000u);
}
__device__ __forceinline__ float u2f(unsigned u){
  return __uint_as_float((u & 0x80000000u) ? (u & 0x7fffffffu) : ~u);
}

// ---------- edge dtype detect (int64 vs int32) ----------
__global__ void k_detect(const int* __restrict__ raw, int* __restrict__ flag){
  if (threadIdx.x == 0 && blockIdx.x == 0){
    int ok = 1;
    for (int i = 0; i < 64; ++i){
      if (raw[2*i + 1] != 0){ ok = 0; break; }            // int64 high words are 0
      unsigned v = (unsigned)raw[2*i];
      if (v >= (unsigned)N_NODES){ ok = 0; break; }
    }
    *flag = ok;   // 1 => int64 layout, 0 => int32 layout
  }
}

__global__ void k_convert(const int* __restrict__ raw, const int* __restrict__ flag,
                          int* __restrict__ esrc, int* __restrict__ edst){
  int e = blockIdx.x * blockDim.x + threadIdx.x;
  if (e >= E_TOT) return;
  if (e < E0){
    if (*flag){ esrc[e] = raw[2*e]; edst[e] = raw[2*(E0 + e)]; }
    else      { esrc[e] = raw[e];   edst[e] = raw[E0 + e];     }
  } else {
    int n = e - E0;        // self loops
    esrc[e] = n; edst[e] = n;
  }
}

// ---------- v[k][u] = sum_c W1[k, h*256+c] * att_{src,dst}[h, c] ----------
// u = h (src) or 8+h (dst). 1024 threads: thread = (k,h), does both dots.
__global__ __launch_bounds__(256) void k_prep(const float* __restrict__ W1,
                                              const float* __restrict__ att_src,
                                              const float* __restrict__ att_dst,
                                              float* __restrict__ vv){
  int t = blockIdx.x*256 + threadIdx.x;      // 0..1023
  int k = t >> 3, h = t & 7;
  const float* wrow = W1 + (size_t)k*HC + h*CHN;
  const float* as   = att_src + h*CHN;
  const float* ad   = att_dst + h*CHN;
  float s = 0.f, d = 0.f;
  #pragma unroll 4
  for (int c = 0; c < CHN; c += 4){
    float4 w = *reinterpret_cast<const float4*>(wrow + c);
    float4 a = *reinterpret_cast<const float4*>(as + c);
    float4 b = *reinterpret_cast<const float4*>(ad + c);
    s += w.x*a.x + w.y*a.y + w.z*a.z + w.w*a.w;
    d += w.x*b.x + w.y*b.y + w.z*b.z + w.w*b.w;
  }
  vv[k*16 + h]     = s;
  vv[k*16 + 8 + h] = d;
}

// ---------- a_src/a_dst [N,8] = x @ v ----------
__global__ __launch_bounds__(128) void k_attdot(const float* __restrict__ x,
                                                const float* __restrict__ vv,
                                                float* __restrict__ a_src,
                                                float* __restrict__ a_dst){
  __shared__ float s_red[2][16];
  const int n = blockIdx.x, k = threadIdx.x;
  const float xv = x[(size_t)n*FIN + k];
  const float* vk = vv + k*16;
  float p[16];
  #pragma unroll
  for (int u = 0; u < 16; ++u) p[u] = xv * vk[u];
  #pragma unroll
  for (int o = 1; o < 64; o <<= 1){
    #pragma unroll
    for (int u = 0; u < 16; ++u) p[u] += __shfl_xor(p[u], o);
  }
  if ((k & 63) == 0){
    #pragma unroll
    for (int u = 0; u < 16; ++u) s_red[k >> 6][u] = p[u];
  }
  __syncthreads();
  if (k < 16){
    float s = s_red[0][k] + s_red[1][k];
    if (k < 8) a_src[n*HEADS + k] = s;
    else       a_dst[n*HEADS + (k - 8)] = s;
  }
}

// ---------- CSR build ----------
__global__ void k_count(const int* __restrict__ edst, int* __restrict__ deg){
  int e = blockIdx.x*256 + threadIdx.x;
  if (e < E_TOT) atomicAdd(&deg[edst[e]], 1);
}

__global__ __launch_bounds__(256) void k_scan(const int* __restrict__ deg,
                                              int* __restrict__ offs){
  __shared__ int sums[256];
  const int tid = threadIdx.x;
  const int CHK = 40;                       // 256*40 = 10240 >= 10000
  int base = tid*CHK;
  int vals[CHK];
  int local = 0;
  #pragma unroll
  for (int i = 0; i < CHK; ++i){
    int idx = base + i;
    int v = (idx < N_NODES) ? deg[idx] : 0;
    vals[i] = local;
    local += v;
  }
  sums[tid] = local;
  __syncthreads();
  for (int o = 1; o < 256; o <<= 1){
    int t = (tid >= o) ? sums[tid - o] : 0;
    __syncthreads();
    sums[tid] += t;
    __syncthreads();
  }
  int boff = (tid == 0) ? 0 : sums[tid - 1];
  #pragma unroll
  for (int i = 0; i < CHK; ++i){
    int idx = base + i;
    if (idx < N_NODES) offs[idx] = boff + vals[i];
  }
  if (tid == 255) offs[N_NODES] = sums[255];
}

__global__ void k_scatter(const int* __restrict__ esrc, const int* __restrict__ edst,
                          const int* __restrict__ offs, int* __restrict__ cursor,
                          int* __restrict__ csr_src){
  int e = blockIdx.x*256 + threadIdx.x;
  if (e < E_TOT){
    int d = edst[e];
    int pos = offs[d] + atomicAdd(&cursor[d], 1);
    csr_src[pos] = esrc[e];
  }
}

// ---------- layer-1: segment softmax + aggregate x rows (128-dim!) ----------
// agg_x[n, h, :] = sum_e alpha[e,h] * x[src_e, :]
__global__ __launch_bounds__(128) void k_aggx(const float* __restrict__ x,
                                              const float* __restrict__ a_src1,
                                              const float* __restrict__ a_dst1,
                                              const int* __restrict__ offs,
                                              const int* __restrict__ csr_src,
                                              float* __restrict__ agg_x){
  __shared__ float s_e[MAXD][HEADS];      // 4 KB
  __shared__ int s_src[MAXD];
  __shared__ unsigned s_maxu[HEADS];
  __shared__ float s_sum[HEADS];
  __shared__ float s_inv[HEADS];
  __shared__ float s_ad[HEADS];
  const int n = blockIdx.x, tid = threadIdx.x;
  const int start = offs[n];
  int deg = offs[n+1] - start;
  if (deg > MAXD) deg = MAXD;   // Poisson(5)+1: max deg ~25, never hit
  if (tid < HEADS){
    s_maxu[tid] = 0u;           // f2u-encoded; 0u < any finite value's code
    s_sum[tid] = 0.f;
    s_ad[tid] = a_dst1[n*HEADS + tid];
  }
  for (int i = tid; i < deg; i += 128) s_src[i] = csr_src[start + i];
  __syncthreads();
  const int tot = deg*HEADS;
  for (int i = tid; i < tot; i += 128){
    int e = i >> 3, hh = i & 7;
    float v = a_src1[s_src[e]*HEADS + hh] + s_ad[hh];
    v = (v >= 0.f) ? v : NEG*v;           // leaky_relu
    s_e[e][hh] = v;
    atomicMax(&s_maxu[hh], f2u(v));
  }
  __syncthreads();
  for (int i = tid; i < tot; i += 128){
    int e = i >> 3, hh = i & 7;
    float v = expf(s_e[e][hh] - u2f(s_maxu[hh]));
    s_e[e][hh] = v;
    atomicAdd(&s_sum[hh], v);
  }
  __syncthreads();
  if (tid < HEADS) s_inv[tid] = 1.f/(s_sum[tid] + 1e-16f);
  __syncthreads();
  for (int i = tid; i < tot; i += 128) s_e[i>>3][i&7] *= s_inv[i&7];
  __syncthreads();
  // aggregate: thread = feature k, acc per head
  float acc[HEADS] = {0,0,0,0,0,0,0,0};
  for (int e = 0; e < deg; ++e){
    float xv = x[(size_t)s_src[e]*FIN + tid];   // 512B coalesced per edge
    #pragma unroll
    for (int h = 0; h < HEADS; ++h) acc[h] = fmaf(s_e[e][h], xv, acc[h]);
  }
  #pragma unroll
  for (int h = 0; h < HEADS; ++h)
    agg_x[(size_t)n*(HEADS*FIN) + h*FIN + tid] = acc[h];
}

// ---------- block-diagonal GEMM: out1[:,h blk] = agg_x[:,h,:] @ W1[:,h blk] ----------
// 128x128 tile, 256 threads, 8x8 micro-tile, BK=16, K=128. + bias + ELU.
#define BM 128
#define BN 128
#define BK 16
__global__ __launch_bounds__(256) void k_gemmh(const float* __restrict__ agg_x,
                                               const float* __restrict__ W1,
                                               const float* __restrict__ b1,
                                               float* __restrict__ out1){
  __shared__ float As[BK][BM];   // 8 KB
  __shared__ float Bs[BK][BN];   // 8 KB
  const int tid = threadIdx.x;
  const int h  = blockIdx.x >> 1;          // head 0..7
  const int ct = blockIdx.x & 1;           // col-tile within head (256 = 2*128)
  const int by = blockIdx.y;               // row tile 0..78
  const int colbase = h*CHN + ct*BN;
  const int tx = tid & 15, ty = tid >> 4;
  float acc[8][8] = {};

  const int a_m0 = tid >> 2;           // 0..63 (+64)
  const int a_kq = (tid & 3) * 4;      // k quad
  const int b_k0 = tid >> 5;           // 0..7 (+8)
  const int b_n  = (tid & 31) * 4;     // 0..124

  for (int k0 = 0; k0 < FIN; k0 += BK){
    #pragma unroll
    for (int tt = 0; tt < 2; ++tt){
      int m = a_m0 + 64*tt;
      int row = by*BM + m;
      float4 av = make_float4(0.f,0.f,0.f,0.f);
      if (row < N_NODES)
        av = *reinterpret_cast<const float4*>(agg_x + (size_t)row*(HEADS*FIN) + h*FIN + k0 + a_kq);
      As[a_kq+0][m] = av.x; As[a_kq+1][m] = av.y;
      As[a_kq+2][m] = av.z; As[a_kq+3][m] = av.w;
    }
    #pragma unroll
    for (int tt = 0; tt < 2; ++tt){
      int kk = b_k0 + 8*tt;
      float4 bv = *reinterpret_cast<const float4*>(W1 + (size_t)(k0 + kk)*HC + colbase + b_n);
      *reinterpret_cast<float4*>(&Bs[kk][b_n]) = bv;
    }
    __syncthreads();
    #pragma unroll
    for (int kk = 0; kk < BK; ++kk){
      float4 a0 = *reinterpret_cast<const float4*>(&As[kk][ty*8]);
      float4 a1 = *reinterpret_cast<const float4*>(&As[kk][ty*8 + 4]);
      float4 b0 = *reinterpret_cast<const float4*>(&Bs[kk][tx*8]);
      float4 b1v = *reinterpret_cast<const float4*>(&Bs[kk][tx*8 + 4]);
      float aa[8] = {a0.x,a0.y,a0.z,a0.w,a1.x,a1.y,a1.z,a1.w};
      float bb[8] = {b0.x,b0.y,b0.z,b0.w,b1v.x,b1v.y,b1v.z,b1v.w};
      #pragma unroll
      for (int i = 0; i < 8; ++i)
        #pragma unroll
        for (int j = 0; j < 8; ++j)
          acc[i][j] = fmaf(aa[i], bb[j], acc[i][j]);
    }
    __syncthreads();
  }
  const int row0 = by*BM + ty*8;
  const int col0 = colbase + tx*8;
  #pragma unroll
  for (int i = 0; i < 8; ++i){
    int r = row0 + i;
    if (r < N_NODES){
      float o[8];
      #pragma unroll
      for (int j = 0; j < 8; ++j){
        float v = acc[i][j] + b1[col0 + j];
        o[j] = (v > 0.f) ? v : (expf(v) - 1.f);     // fused ELU
      }
      *reinterpret_cast<float4*>(out1 + (size_t)r*HC + col0)     = make_float4(o[0],o[1],o[2],o[3]);
      *reinterpret_cast<float4*>(out1 + (size_t)r*HC + col0 + 4) = make_float4(o[4],o[5],o[6],o[7]);
    }
  }
}

// ---------- layer-2 GEMM + attention dots ----------
__global__ __launch_bounds__(256) void k_l2(const float* __restrict__ out1,
                                            const float* __restrict__ W2,
                                            const float* __restrict__ as2,
                                            const float* __restrict__ ad2,
                                            float* __restrict__ h2,
                                            float* __restrict__ a_src2,
                                            float* __restrict__ a_dst2){
  __shared__ float red[4][NC];
  __shared__ float sh[NC];
  const int n = blockIdx.x, tid = threadIdx.x;
  float acc[NC] = {};
  const float* row = out1 + (size_t)n*HC;
  for (int k = tid; k < HC; k += 256){
    float v = row[k];
    const float* w = W2 + (size_t)k*NC;
    #pragma unroll
    for (int j = 0; j < NC; ++j) acc[j] = fmaf(v, w[j], acc[j]);
  }
  #pragma unroll
  for (int o = 1; o < 64; o <<= 1){
    #pragma unroll
    for (int j = 0; j < NC; ++j) acc[j] += __shfl_xor(acc[j], o);
  }
  const int wave = tid >> 6, lane = tid & 63;
  if (lane == 0){
    #pragma unroll
    for (int j = 0; j < NC; ++j) red[wave][j] = acc[j];
  }
  __syncthreads();
  if (tid < NC){
    float s = red[0][tid] + red[1][tid] + red[2][tid] + red[3][tid];
    h2[n*NC + tid] = s;
    sh[tid] = s;
  }
  __syncthreads();
  if (tid == 0){
    float s = 0.f, d = 0.f;
    #pragma unroll
    for (int j = 0; j < NC; ++j){
      s = fmaf(sh[j], as2[j], s);
      d = fmaf(sh[j], ad2[j], d);
    }
    a_src2[n] = s;
    a_dst2[n] = d;
  }
}

// ---------- layer-2 aggregation + sigmoid ----------
__global__ __launch_bounds__(64) void k_agg2(const float* __restrict__ h2,
                                             const float* __restrict__ a_src2,
                                             const float* __restrict__ a_dst2,
                                             const int* __restrict__ offs,
                                             const int* __restrict__ csr_src,
                                             const float* __restrict__ b2,
                                             float* __restrict__ out){
  const int n = blockIdx.x, lane = threadIdx.x;
  const int start = offs[n];
  const int deg = offs[n+1] - start;
  const float ad = a_dst2[n];
  float m = -INFINITY;
  for (int i = lane; i < deg; i += 64){
    float e = a_src2[csr_src[start + i]] + ad;
    e = (e >= 0.f) ? e : NEG*e;
    m = fmaxf(m, e);
  }
  #pragma unroll
  for (int o = 1; o < 64; o <<= 1) m = fmaxf(m, __shfl_xor(m, o));
  float s = 0.f;
  for (int i = lane; i < deg; i += 64){
    float e = a_src2[csr_src[start + i]] + ad;
    e = (e >= 0.f) ? e : NEG*e;
    s += expf(e - m);
  }
  #pragma unroll
  for (int o = 1; o < 64; o <<= 1) s += __shfl_xor(s, o);
  const float inv = 1.f/(s + 1e-16f);
  if (lane < NC){
    float acc = 0.f;
    for (int i = 0; i < deg; ++i){
      int src = csr_src[start + i];
      float e = a_src2[src] + ad;
      e = (e >= 0.f) ? e : NEG*e;
      float al = expf(e - m)*inv;
      acc = fmaf(al, h2[src*NC + lane], acc);
    }
    float v = acc + b2[lane];
    out[n*NC + lane] = 1.f/(1.f + expf(-v));
  }
}

// ---------- launch ----------
extern "C" void kernel_launch(void* const* d_in, const int* in_sizes, int n_in,
                              void* d_out, int out_size, void* d_ws, size_t ws_size,
                              hipStream_t stream){
  const float* x   = (const float*)d_in[0];
  const int*   ei  = (const int*)  d_in[1];
  const float* W1  = (const float*)d_in[2];
  const float* as1 = (const float*)d_in[3];
  const float* ad1 = (const float*)d_in[4];
  const float* b1  = (const float*)d_in[5];
  const float* W2  = (const float*)d_in[6];
  const float* as2 = (const float*)d_in[7];
  const float* ad2 = (const float*)d_in[8];
  const float* b2  = (const float*)d_in[9];
  float* out = (float*)d_out;

  char* ws = (char*)d_ws;
  size_t off = 0;
  auto alloc = [&](size_t bytes) -> void* {
    void* p = ws + off;
    off += (bytes + 255) & ~(size_t)255;
    return p;
  };
  float* out1    = (float*)alloc((size_t)N_NODES*HC*4);         // 81.92 MB
  float* agg_x   = (float*)alloc((size_t)N_NODES*HEADS*FIN*4);  // 40.96 MB
  float* vv      = (float*)alloc((size_t)FIN*16*4);             // 8 KB
  float* a_src1  = (float*)alloc((size_t)N_NODES*HEADS*4);
  float* a_dst1  = (float*)alloc((size_t)N_NODES*HEADS*4);
  float* h2      = (float*)alloc((size_t)N_NODES*NC*4);
  float* a_src2  = (float*)alloc((size_t)N_NODES*4);
  float* a_dst2  = (float*)alloc((size_t)N_NODES*4);
  int*   deg     = (int*)alloc((size_t)N_NODES*4);
  int*   offs    = (int*)alloc((size_t)(N_NODES+1)*4);
  int*   cursor  = (int*)alloc((size_t)N_NODES*4);
  int*   esrc    = (int*)alloc((size_t)E_TOT*4);
  int*   edst    = (int*)alloc((size_t)E_TOT*4);
  int*   csr_src = (int*)alloc((size_t)E_TOT*4);
  int*   flag    = (int*)alloc(4);
  (void)ws_size; (void)in_sizes; (void)n_in; (void)out_size;

  hipMemsetAsync(deg,    0, (size_t)N_NODES*4, stream);
  hipMemsetAsync(cursor, 0, (size_t)N_NODES*4, stream);

  k_detect <<<1, 64, 0, stream>>>(ei, flag);
  k_convert<<<(E_TOT + 255)/256, 256, 0, stream>>>(ei, flag, esrc, edst);
  k_prep   <<<4, 256, 0, stream>>>(W1, as1, ad1, vv);
  k_attdot <<<N_NODES, 128, 0, stream>>>(x, vv, a_src1, a_dst1);
  k_count  <<<(E_TOT + 255)/256, 256, 0, stream>>>(edst, deg);
  k_scan   <<<1, 256, 0, stream>>>(deg, offs);
  k_scatter<<<(E_TOT + 255)/256, 256, 0, stream>>>(esrc, edst, offs, cursor, csr_src);
  k_aggx   <<<N_NODES, 128, 0, stream>>>(x, a_src1, a_dst1, offs, csr_src, agg_x);
  k_gemmh  <<<dim3(16, (N_NODES + BM - 1)/BM), 256, 0, stream>>>(agg_x, W1, b1, out1);
  k_l2     <<<N_NODES, 256, 0, stream>>>(out1, W2, as2, ad2, h2, a_src2, a_dst2);
  k_agg2   <<<N_NODES, 64, 0, stream>>>(h2, a_src2, a_dst2, offs, csr_src, b2, out);
}

// Round 4
// 258.829 us; speedup vs baseline: 1.1462x; 1.1462x over previous
//
#include <hip/hip_runtime.h>
#include <math.h>

#define N_NODES 10000
#define N_PAD   10112          // 79*128, agg rows over-allocated for tile reads
#define E0      50000
#define E_TOT   60000
#define FIN     128
#define HEADS   8
#define CHN     256
#define HC      2048
#define NC      10
#define NEG     0.2f
#define MAXD    128

typedef __attribute__((ext_vector_type(8))) short bf16x8;
typedef __attribute__((ext_vector_type(4))) float f32x4;

// ---------- helpers ----------
__device__ __forceinline__ unsigned f2u(float f){
  unsigned u = __float_as_uint(f);
  return (u & 0x80000000u) ? ~u : (u | 0x80000000u);
}
__device__ __forceinline__ float u2f(unsigned u){
  return __uint_as_float((u & 0x80000000u) ? (u & 0x7fffffffu) : ~u);
}
__device__ __forceinline__ unsigned short bf16_rne(float f){
  unsigned u = __float_as_uint(f);
  return (unsigned short)((u + 0x7FFFu + ((u >> 16) & 1u)) >> 16);
}

// ---------- edge dtype detect (int64 vs int32), wave-parallel ----------
__global__ void k_detect(const int* __restrict__ raw, int* __restrict__ flag){
  int t = threadIdx.x;   // 64 threads
  bool bad = (raw[2*t + 1] != 0) || ((unsigned)raw[2*t] >= (unsigned)N_NODES);
  unsigned long long b = __ballot(bad);
  if (t == 0) *flag = (b == 0ull) ? 1 : 0;
}

// ---------- convert + degree count (fused) ----------
__global__ void k_convert(const int* __restrict__ raw, const int* __restrict__ flag,
                          int* __restrict__ esrc, int* __restrict__ edst,
                          int* __restrict__ deg){
  int e = blockIdx.x * blockDim.x + threadIdx.x;
  if (e >= E_TOT) return;
  int s, d;
  if (e < E0){
    if (*flag){ s = raw[2*e]; d = raw[2*(E0 + e)]; }
    else      { s = raw[e];   d = raw[E0 + e];     }
  } else {
    s = d = e - E0;      // self loops
  }
  esrc[e] = s; edst[e] = d;
  atomicAdd(&deg[d], 1);
}

// ---------- vv[k][u] = sum_c W1[k, h*256+c] * att_{src,dst}[h, c] ----------
__global__ __launch_bounds__(256) void k_prep(const float* __restrict__ W1,
                                              const float* __restrict__ att_src,
                                              const float* __restrict__ att_dst,
                                              float* __restrict__ vv){
  int t = blockIdx.x*256 + threadIdx.x;      // 0..1023
  int k = t >> 3, h = t & 7;
  const float* wrow = W1 + (size_t)k*HC + h*CHN;
  const float* as   = att_src + h*CHN;
  const float* ad   = att_dst + h*CHN;
  float s = 0.f, d = 0.f;
  #pragma unroll 4
  for (int c = 0; c < CHN; c += 4){
    float4 w = *reinterpret_cast<const float4*>(wrow + c);
    float4 a = *reinterpret_cast<const float4*>(as + c);
    float4 b = *reinterpret_cast<const float4*>(ad + c);
    s += w.x*a.x + w.y*a.y + w.z*a.z + w.w*a.w;
    d += w.x*b.x + w.y*b.y + w.z*b.z + w.w*b.w;
  }
  vv[k*16 + h]     = s;
  vv[k*16 + 8 + h] = d;
}

// ---------- W1^T split to bf16 hi/lo: w1t[n][k] ----------
__global__ __launch_bounds__(256) void k_prepw(const float* __restrict__ W1,
                                               unsigned short* __restrict__ w1t_hi,
                                               unsigned short* __restrict__ w1t_lo){
  int t = blockIdx.x*256 + threadIdx.x;   // 0..262143
  int k = t >> 11;          // 0..127
  int n = t & 2047;         // coalesced read along n
  float v = W1[(size_t)k*HC + n];
  unsigned short hi = bf16_rne(v);
  float hf = __uint_as_float((unsigned)hi << 16);
  unsigned short lo = bf16_rne(v - hf);
  w1t_hi[(size_t)n*FIN + k] = hi;
  w1t_lo[(size_t)n*FIN + k] = lo;
}

// ---------- a_src/a_dst [N,8] = x @ v ----------
__global__ __launch_bounds__(128) void k_attdot(const float* __restrict__ x,
                                                const float* __restrict__ vv,
                                                float* __restrict__ a_src,
                                                float* __restrict__ a_dst){
  __shared__ float s_red[2][16];
  const int n = blockIdx.x, k = threadIdx.x;
  const float xv = x[(size_t)n*FIN + k];
  const float* vk = vv + k*16;
  float p[16];
  #pragma unroll
  for (int u = 0; u < 16; ++u) p[u] = xv * vk[u];
  #pragma unroll
  for (int o = 1; o < 64; o <<= 1){
    #pragma unroll
    for (int u = 0; u < 16; ++u) p[u] += __shfl_xor(p[u], o);
  }
  if ((k & 63) == 0){
    #pragma unroll
    for (int u = 0; u < 16; ++u) s_red[k >> 6][u] = p[u];
  }
  __syncthreads();
  if (k < 16){
    float s = s_red[0][k] + s_red[1][k];
    if (k < 8) a_src[n*HEADS + k] = s;
    else       a_dst[n*HEADS + (k - 8)] = s;
  }
}

// ---------- CSR scan ----------
__global__ __launch_bounds__(256) void k_scan(const int* __restrict__ deg,
                                              int* __restrict__ offs){
  __shared__ int sums[256];
  const int tid = threadIdx.x;
  const int CHK = 40;                       // 256*40 = 10240 >= 10000
  int base = tid*CHK;
  int vals[CHK];
  int local = 0;
  #pragma unroll
  for (int i = 0; i < CHK; ++i){
    int idx = base + i;
    int v = (idx < N_NODES) ? deg[idx] : 0;
    vals[i] = local;
    local += v;
  }
  sums[tid] = local;
  __syncthreads();
  for (int o = 1; o < 256; o <<= 1){
    int t = (tid >= o) ? sums[tid - o] : 0;
    __syncthreads();
    sums[tid] += t;
    __syncthreads();
  }
  int boff = (tid == 0) ? 0 : sums[tid - 1];
  #pragma unroll
  for (int i = 0; i < CHK; ++i){
    int idx = base + i;
    if (idx < N_NODES) offs[idx] = boff + vals[i];
  }
  if (tid == 255) offs[N_NODES] = sums[255];
}

__global__ void k_scatter(const int* __restrict__ esrc, const int* __restrict__ edst,
                          const int* __restrict__ offs, int* __restrict__ cursor,
                          int* __restrict__ csr_src){
  int e = blockIdx.x*256 + threadIdx.x;
  if (e < E_TOT){
    int d = edst[e];
    int pos = offs[d] + atomicAdd(&cursor[d], 1);
    csr_src[pos] = esrc[e];
  }
}

// ---------- layer-1: segment softmax + aggregate x rows -> bf16 hi/lo ----------
__global__ __launch_bounds__(128) void k_aggx(const float* __restrict__ x,
                                              const float* __restrict__ a_src1,
                                              const float* __restrict__ a_dst1,
                                              const int* __restrict__ offs,
                                              const int* __restrict__ csr_src,
                                              unsigned short* __restrict__ agg_hi,
                                              unsigned short* __restrict__ agg_lo){
  __shared__ float s_e[MAXD][HEADS];      // 4 KB
  __shared__ int s_src[MAXD];
  __shared__ unsigned s_maxu[HEADS];
  __shared__ float s_sum[HEADS];
  __shared__ float s_inv[HEADS];
  __shared__ float s_ad[HEADS];
  const int n = blockIdx.x, tid = threadIdx.x;
  const int start = offs[n];
  int deg = offs[n+1] - start;
  if (deg > MAXD) deg = MAXD;   // Poisson(5)+1: never hit
  if (tid < HEADS){
    s_maxu[tid] = 0u;
    s_sum[tid] = 0.f;
    s_ad[tid] = a_dst1[n*HEADS + tid];
  }
  for (int i = tid; i < deg; i += 128) s_src[i] = csr_src[start + i];
  __syncthreads();
  const int tot = deg*HEADS;
  for (int i = tid; i < tot; i += 128){
    int e = i >> 3, hh = i & 7;
    float v = a_src1[s_src[e]*HEADS + hh] + s_ad[hh];
    v = (v >= 0.f) ? v : NEG*v;           // leaky_relu
    s_e[e][hh] = v;
    atomicMax(&s_maxu[hh], f2u(v));
  }
  __syncthreads();
  for (int i = tid; i < tot; i += 128){
    int e = i >> 3, hh = i & 7;
    float v = expf(s_e[e][hh] - u2f(s_maxu[hh]));
    s_e[e][hh] = v;
    atomicAdd(&s_sum[hh], v);
  }
  __syncthreads();
  if (tid < HEADS) s_inv[tid] = 1.f/(s_sum[tid] + 1e-16f);
  __syncthreads();
  for (int i = tid; i < tot; i += 128) s_e[i>>3][i&7] *= s_inv[i&7];
  __syncthreads();
  float acc[HEADS] = {0,0,0,0,0,0,0,0};
  for (int e = 0; e < deg; ++e){
    float xv = x[(size_t)s_src[e]*FIN + tid];
    #pragma unroll
    for (int h = 0; h < HEADS; ++h) acc[h] = fmaf(s_e[e][h], xv, acc[h]);
  }
  #pragma unroll
  for (int h = 0; h < HEADS; ++h){
    float v = acc[h];
    unsigned short hi = bf16_rne(v);
    float hf = __uint_as_float((unsigned)hi << 16);
    unsigned short lo = bf16_rne(v - hf);
    size_t idx = ((size_t)n*HEADS + h)*FIN + tid;
    agg_hi[idx] = hi;
    agg_lo[idx] = lo;
  }
}

// ---------- fused MFMA GEMM: ELU(agg@W1+b1) @ W2 -> h2 partials ----------
// Block 128 rows x 128 cols; 4 waves (2x2), wave tile 64x64, 4x4 16x16x32 frags.
// bf16x3 split (hi*hi + hi*lo + lo*hi), fp32 acc. No LDS in main loop.
__global__ __launch_bounds__(256) void k_gemmf(const unsigned short* __restrict__ agg_hi,
                                               const unsigned short* __restrict__ agg_lo,
                                               const unsigned short* __restrict__ w1t_hi,
                                               const unsigned short* __restrict__ w1t_lo,
                                               const float* __restrict__ b1,
                                               const float* __restrict__ W2,
                                               float* __restrict__ h2_part){
  __shared__ float W2s[128][NC];       // 5 KB
  __shared__ float b1s[128];
  __shared__ float h2s[2][128][NC];    // 10 KB, [wc][row][j]
  const int tid = threadIdx.x;
  const int bx = blockIdx.x;           // 0..15 (head = bx>>1)
  const int by = blockIdx.y;           // 0..78
  const int h  = bx >> 1;
  const int colbase = bx*128;
  const int wave = tid >> 6, lane = tid & 63;
  const int wr = wave >> 1, wc = wave & 1;
  const int nl = lane & 15, g = lane >> 4;

  for (int i = tid; i < 128*NC; i += 256){
    int c = i/NC, j = i - c*NC;
    W2s[c][j] = W2[(size_t)(colbase + c)*NC + j];
  }
  if (tid < 128) b1s[tid] = b1[colbase + tid];

  f32x4 zero4 = {0.f, 0.f, 0.f, 0.f};
  f32x4 acc[4][4];
  #pragma unroll
  for (int fm = 0; fm < 4; ++fm)
    #pragma unroll
    for (int fn = 0; fn < 4; ++fn) acc[fm][fn] = zero4;

  // A: lane -> row = (l&15), k = kc*32 + (l>>4)*8 + j   (16B contiguous)
  // B: lane -> col = (l&15), k same mapping (W1t is [n][k])
  const size_t abase = (((size_t)(by*128 + wr*64 + nl))*HEADS + h)*FIN + g*8;
  const size_t bbase = ((size_t)(colbase + wc*64 + nl))*FIN + g*8;

  #pragma unroll
  for (int kc = 0; kc < 4; ++kc){
    bf16x8 ah[4], al[4], bh[4], bl[4];
    #pragma unroll
    for (int f = 0; f < 4; ++f){
      size_t ao = abase + (size_t)f*16*HEADS*FIN + kc*32;
      size_t bo = bbase + (size_t)f*16*FIN + kc*32;
      ah[f] = *reinterpret_cast<const bf16x8*>(agg_hi + ao);
      al[f] = *reinterpret_cast<const bf16x8*>(agg_lo + ao);
      bh[f] = *reinterpret_cast<const bf16x8*>(w1t_hi + bo);
      bl[f] = *reinterpret_cast<const bf16x8*>(w1t_lo + bo);
    }
    #pragma unroll
    for (int fm = 0; fm < 4; ++fm)
      #pragma unroll
      for (int fn = 0; fn < 4; ++fn){
        acc[fm][fn] = __builtin_amdgcn_mfma_f32_16x16x32_bf16(ah[fm], bh[fn], acc[fm][fn], 0, 0, 0);
        acc[fm][fn] = __builtin_amdgcn_mfma_f32_16x16x32_bf16(ah[fm], bl[fn], acc[fm][fn], 0, 0, 0);
        acc[fm][fn] = __builtin_amdgcn_mfma_f32_16x16x32_bf16(al[fm], bh[fn], acc[fm][fn], 0, 0, 0);
      }
  }
  __syncthreads();   // W2s/b1s staged

  // D frag: col = fn*16 + nl, row = fm*16 + g*4 + r  (within wave 64x64)
  #pragma unroll
  for (int fm = 0; fm < 4; ++fm)
    #pragma unroll
    for (int fn = 0; fn < 4; ++fn){
      float bb = b1s[wc*64 + fn*16 + nl];
      #pragma unroll
      for (int r = 0; r < 4; ++r){
        float v = acc[fm][fn][r] + bb;
        acc[fm][fn][r] = (v > 0.f) ? v : (__expf(v) - 1.f);   // fused ELU
      }
    }

  for (int j = 0; j < NC; ++j){
    float hp[4][4];
    #pragma unroll
    for (int fm = 0; fm < 4; ++fm)
      #pragma unroll
      for (int r = 0; r < 4; ++r) hp[fm][r] = 0.f;
    #pragma unroll
    for (int fn = 0; fn < 4; ++fn){
      float w = W2s[wc*64 + fn*16 + nl][j];
      #pragma unroll
      for (int fm = 0; fm < 4; ++fm)
        #pragma unroll
        for (int r = 0; r < 4; ++r)
          hp[fm][r] = fmaf(acc[fm][fn][r], w, hp[fm][r]);
    }
    #pragma unroll
    for (int o = 1; o < 16; o <<= 1){
      #pragma unroll
      for (int fm = 0; fm < 4; ++fm)
        #pragma unroll
        for (int r = 0; r < 4; ++r)
          hp[fm][r] += __shfl_xor(hp[fm][r], o);
    }
    if (nl == 0){
      #pragma unroll
      for (int fm = 0; fm < 4; ++fm)
        #pragma unroll
        for (int r = 0; r < 4; ++r)
          h2s[wc][wr*64 + fm*16 + g*4 + r][j] = hp[fm][r];
    }
  }
  __syncthreads();
  for (int i = tid; i < 128*NC; i += 256){
    int rl = i/NC, j = i - rl*NC;
    int row = by*128 + rl;
    if (row < N_NODES)
      h2_part[((size_t)bx*N_NODES + row)*NC + j] = h2s[0][rl][j] + h2s[1][rl][j];
  }
}

// ---------- reduce h2 partials + layer-2 attention dots ----------
__global__ __launch_bounds__(256) void k_h2fin(const float* __restrict__ h2_part,
                                               const float* __restrict__ as2,
                                               const float* __restrict__ ad2,
                                               float* __restrict__ h2,
                                               float* __restrict__ a_src2,
                                               float* __restrict__ a_dst2){
  int n = blockIdx.x*256 + threadIdx.x;
  if (n >= N_NODES) return;
  float s[NC];
  #pragma unroll
  for (int j = 0; j < NC; ++j) s[j] = 0.f;
  for (int bx = 0; bx < 16; ++bx){
    #pragma unroll
    for (int j = 0; j < NC; ++j)
      s[j] += h2_part[((size_t)bx*N_NODES + n)*NC + j];
  }
  float ds = 0.f, dd = 0.f;
  #pragma unroll
  for (int j = 0; j < NC; ++j){
    h2[(size_t)n*NC + j] = s[j];
    ds = fmaf(s[j], as2[j], ds);
    dd = fmaf(s[j], ad2[j], dd);
  }
  a_src2[n] = ds;
  a_dst2[n] = dd;
}

// ---------- layer-2 aggregation + sigmoid ----------
__global__ __launch_bounds__(64) void k_agg2(const float* __restrict__ h2,
                                             const float* __restrict__ a_src2,
                                             const float* __restrict__ a_dst2,
                                             const int* __restrict__ offs,
                                             const int* __restrict__ csr_src,
                                             const float* __restrict__ b2,
                                             float* __restrict__ out){
  const int n = blockIdx.x, lane = threadIdx.x;
  const int start = offs[n];
  const int deg = offs[n+1] - start;
  const float ad = a_dst2[n];
  float m = -INFINITY;
  for (int i = lane; i < deg; i += 64){
    float e = a_src2[csr_src[start + i]] + ad;
    e = (e >= 0.f) ? e : NEG*e;
    m = fmaxf(m, e);
  }
  #pragma unroll
  for (int o = 1; o < 64; o <<= 1) m = fmaxf(m, __shfl_xor(m, o));
  float s = 0.f;
  for (int i = lane; i < deg; i += 64){
    float e = a_src2[csr_src[start + i]] + ad;
    e = (e >= 0.f) ? e : NEG*e;
    s += expf(e - m);
  }
  #pragma unroll
  for (int o = 1; o < 64; o <<= 1) s += __shfl_xor(s, o);
  const float inv = 1.f/(s + 1e-16f);
  if (lane < NC){
    float acc = 0.f;
    for (int i = 0; i < deg; ++i){
      int src = csr_src[start + i];
      float e = a_src2[src] + ad;
      e = (e >= 0.f) ? e : NEG*e;
      float al = expf(e - m)*inv;
      acc = fmaf(al, h2[(size_t)src*NC + lane], acc);
    }
    float v = acc + b2[lane];
    out[n*NC + lane] = 1.f/(1.f + expf(-v));
  }
}

// ---------- launch ----------
extern "C" void kernel_launch(void* const* d_in, const int* in_sizes, int n_in,
                              void* d_out, int out_size, void* d_ws, size_t ws_size,
                              hipStream_t stream){
  const float* x   = (const float*)d_in[0];
  const int*   ei  = (const int*)  d_in[1];
  const float* W1  = (const float*)d_in[2];
  const float* as1 = (const float*)d_in[3];
  const float* ad1 = (const float*)d_in[4];
  const float* b1  = (const float*)d_in[5];
  const float* W2  = (const float*)d_in[6];
  const float* as2 = (const float*)d_in[7];
  const float* ad2 = (const float*)d_in[8];
  const float* b2  = (const float*)d_in[9];
  float* out = (float*)d_out;

  char* ws = (char*)d_ws;
  size_t off = 0;
  auto alloc = [&](size_t bytes) -> void* {
    void* p = ws + off;
    off += (bytes + 255) & ~(size_t)255;
    return p;
  };
  unsigned short* agg_hi = (unsigned short*)alloc((size_t)N_PAD*HEADS*FIN*2);  // 20.7 MB
  unsigned short* agg_lo = (unsigned short*)alloc((size_t)N_PAD*HEADS*FIN*2);  // 20.7 MB
  unsigned short* w1t_hi = (unsigned short*)alloc((size_t)HC*FIN*2);           // 0.5 MB
  unsigned short* w1t_lo = (unsigned short*)alloc((size_t)HC*FIN*2);           // 0.5 MB
  float* h2_part = (float*)alloc((size_t)16*N_NODES*NC*4);                     // 6.4 MB
  float* vv      = (float*)alloc((size_t)FIN*16*4);
  float* a_src1  = (float*)alloc((size_t)N_NODES*HEADS*4);
  float* a_dst1  = (float*)alloc((size_t)N_NODES*HEADS*4);
  float* h2      = (float*)alloc((size_t)N_NODES*NC*4);
  float* a_src2  = (float*)alloc((size_t)N_NODES*4);
  float* a_dst2  = (float*)alloc((size_t)N_NODES*4);
  int*   deg     = (int*)alloc((size_t)N_NODES*4);
  int*   offs    = (int*)alloc((size_t)(N_NODES+1)*4);
  int*   cursor  = (int*)alloc((size_t)N_NODES*4);
  int*   esrc    = (int*)alloc((size_t)E_TOT*4);
  int*   edst    = (int*)alloc((size_t)E_TOT*4);
  int*   csr_src = (int*)alloc((size_t)E_TOT*4);
  int*   flag    = (int*)alloc(4);
  (void)ws_size; (void)in_sizes; (void)n_in; (void)out_size;

  hipMemsetAsync(deg,    0, (size_t)N_NODES*4, stream);
  hipMemsetAsync(cursor, 0, (size_t)N_NODES*4, stream);

  k_detect <<<1, 64, 0, stream>>>(ei, flag);
  k_convert<<<(E_TOT + 255)/256, 256, 0, stream>>>(ei, flag, esrc, edst, deg);
  k_prep   <<<4, 256, 0, stream>>>(W1, as1, ad1, vv);
  k_prepw  <<<(HC*FIN)/256, 256, 0, stream>>>(W1, w1t_hi, w1t_lo);
  k_attdot <<<N_NODES, 128, 0, stream>>>(x, vv, a_src1, a_dst1);
  k_scan   <<<1, 256, 0, stream>>>(deg, offs);
  k_scatter<<<(E_TOT + 255)/256, 256, 0, stream>>>(esrc, edst, offs, cursor, csr_src);
  k_aggx   <<<N_NODES, 128, 0, stream>>>(x, a_src1, a_dst1, offs, csr_src, agg_hi, agg_lo);
  k_gemmf  <<<dim3(16, N_PAD/128), 256, 0, stream>>>(agg_hi, agg_lo, w1t_hi, w1t_lo, b1, W2, h2_part);
  k_h2fin  <<<(N_NODES + 255)/256, 256, 0, stream>>>(h2_part, as2, ad2, h2, a_src2, a_dst2);
  k_agg2   <<<N_NODES, 64, 0, stream>>>(h2, a_src2, a_dst2, offs, csr_src, b2, out);
}

// Round 6
// 243.710 us; speedup vs baseline: 1.2173x; 1.0620x over previous
//
#include <hip/hip_runtime.h>
#include <math.h>

#define N_NODES 10000
#define N_PAD   10112          // 79*128
#define E0      50000
#define E_TOT   60000
#define FIN     128
#define HEADS   8
#define CHN     256
#define HC      2048
#define NC      10
#define NEG     0.2f
#define MAXD    128
#define MAXD2   64

typedef __attribute__((ext_vector_type(8))) short bf16x8;
typedef __attribute__((ext_vector_type(4))) float f32x4;

// ---------- helpers ----------
__device__ __forceinline__ unsigned f2u(float f){
  unsigned u = __float_as_uint(f);
  return (u & 0x80000000u) ? ~u : (u | 0x80000000u);
}
__device__ __forceinline__ float u2f(unsigned u){
  return __uint_as_float((u & 0x80000000u) ? (u & 0x7fffffffu) : ~u);
}
__device__ __forceinline__ unsigned short bf16_rne(float f){
  unsigned u = __float_as_uint(f);
  return (unsigned short)((u + 0x7FFFu + ((u >> 16) & 1u)) >> 16);
}

// ---------- init: zero deg/cursor + edge dtype detect ----------
__global__ void k_init(const int* __restrict__ raw, int* __restrict__ flag,
                       int* __restrict__ deg, int* __restrict__ cursor){
  int t = blockIdx.x*256 + threadIdx.x;
  if (t < N_NODES){ deg[t] = 0; cursor[t] = 0; }
  if (blockIdx.x == 0 && threadIdx.x < 64){
    int i = threadIdx.x;
    bool bad = (raw[2*i + 1] != 0) || ((unsigned)raw[2*i] >= (unsigned)N_NODES);
    unsigned long long b = __ballot(bad);
    if (i == 0) *flag = (b == 0ull) ? 1 : 0;
  }
}

// ---------- convert + degree count ----------
__global__ void k_convert(const int* __restrict__ raw, const int* __restrict__ flag,
                          int* __restrict__ esrc, int* __restrict__ edst,
                          int* __restrict__ deg){
  int e = blockIdx.x * blockDim.x + threadIdx.x;
  if (e >= E_TOT) return;
  int s, d;
  if (e < E0){
    if (*flag){ s = raw[2*e]; d = raw[2*(E0 + e)]; }
    else      { s = raw[e];   d = raw[E0 + e];     }
  } else {
    s = d = e - E0;      // self loops
  }
  esrc[e] = s; edst[e] = d;
  atomicAdd(&deg[d], 1);
}

// ---------- weight prep: W1^T bf16 hi/lo, W2^T f32, vv attention vectors ----------
__global__ __launch_bounds__(256) void k_prepw(const float* __restrict__ W1,
                                               const float* __restrict__ att_src,
                                               const float* __restrict__ att_dst,
                                               const float* __restrict__ W2,
                                               unsigned short* __restrict__ w1t_hi,
                                               unsigned short* __restrict__ w1t_lo,
                                               float* __restrict__ W2t,
                                               float* __restrict__ vv){
  int t = blockIdx.x*256 + threadIdx.x;      // 0..262143
  {
    int k = t >> 11;          // 0..127
    int n = t & 2047;
    float v = W1[(size_t)k*HC + n];
    unsigned short hi = bf16_rne(v);
    float hf = __uint_as_float((unsigned)hi << 16);
    unsigned short lo = bf16_rne(v - hf);
    w1t_hi[(size_t)n*FIN + k] = hi;
    w1t_lo[(size_t)n*FIN + k] = lo;
  }
  if (t < HC*NC){            // W2t[j][k] = W2[k][j]
    int j = t >> 11, k = t & 2047;
    W2t[(size_t)j*HC + k] = W2[(size_t)k*NC + j];
  }
  if (t < FIN*HEADS){        // vv[k][u]
    int k = t >> 3, h = t & 7;
    const float* wrow = W1 + (size_t)k*HC + h*CHN;
    const float* as   = att_src + h*CHN;
    const float* ad   = att_dst + h*CHN;
    float s = 0.f, d = 0.f;
    #pragma unroll 4
    for (int c = 0; c < CHN; c += 4){
      float4 w = *reinterpret_cast<const float4*>(wrow + c);
      float4 a = *reinterpret_cast<const float4*>(as + c);
      float4 b = *reinterpret_cast<const float4*>(ad + c);
      s += w.x*a.x + w.y*a.y + w.z*a.z + w.w*a.w;
      d += w.x*b.x + w.y*b.y + w.z*b.z + w.w*b.w;
    }
    vv[k*16 + h]     = s;
    vv[k*16 + 8 + h] = d;
  }
}

// ---------- a_src/a_dst [N,8] = x @ vv : one wave per node, 2 shfl total ----------
__global__ __launch_bounds__(256) void k_attdot(const float* __restrict__ x,
                                                const float* __restrict__ vv,
                                                float* __restrict__ a_src,
                                                float* __restrict__ a_dst){
  const int wave = threadIdx.x >> 6, lane = threadIdx.x & 63;
  const int n = blockIdx.x*4 + wave;
  const int u = lane & 15, c = lane >> 4;
  const float* xr = x + (size_t)n*FIN + c*32;
  float acc = 0.f;
  #pragma unroll
  for (int q = 0; q < 8; ++q){
    float4 xv = *reinterpret_cast<const float4*>(xr + q*4);
    int k = c*32 + q*4;
    acc = fmaf(xv.x, vv[(k+0)*16 + u], acc);
    acc = fmaf(xv.y, vv[(k+1)*16 + u], acc);
    acc = fmaf(xv.z, vv[(k+2)*16 + u], acc);
    acc = fmaf(xv.w, vv[(k+3)*16 + u], acc);
  }
  acc += __shfl_xor(acc, 16);
  acc += __shfl_xor(acc, 32);
  if (c == 0){
    if (u < 8) a_src[n*HEADS + u] = acc;
    else       a_dst[n*HEADS + (u - 8)] = acc;
  }
}

// ---------- CSR scan (single block, 1024 threads) ----------
__global__ __launch_bounds__(1024) void k_scan(const int* __restrict__ deg,
                                               int* __restrict__ offs){
  __shared__ int sums[1024];
  const int tid = threadIdx.x;
  int base = tid*10;
  int vals[10];
  int local = 0;
  #pragma unroll
  for (int i = 0; i < 10; ++i){
    int idx = base + i;
    int v = (idx < N_NODES) ? deg[idx] : 0;
    vals[i] = local;
    local += v;
  }
  sums[tid] = local;
  __syncthreads();
  for (int o = 1; o < 1024; o <<= 1){
    int t = (tid >= o) ? sums[tid - o] : 0;
    __syncthreads();
    sums[tid] += t;
    __syncthreads();
  }
  int boff = (tid == 0) ? 0 : sums[tid - 1];
  #pragma unroll
  for (int i = 0; i < 10; ++i){
    int idx = base + i;
    if (idx < N_NODES) offs[idx] = boff + vals[i];
  }
  if (tid == 1023) offs[N_NODES] = sums[1023];
}

__global__ void k_scatter(const int* __restrict__ esrc, const int* __restrict__ edst,
                          const int* __restrict__ offs, int* __restrict__ cursor,
                          int* __restrict__ csr_src){
  int e = blockIdx.x*256 + threadIdx.x;
  if (e < E_TOT){
    int d = edst[e];
    int pos = offs[d] + atomicAdd(&cursor[d], 1);
    csr_src[pos] = esrc[e];
  }
}

// ---------- layer-1: segment softmax + aggregate x rows -> bf16 hi/lo ----------
__global__ __launch_bounds__(128) void k_aggx(const float* __restrict__ x,
                                              const float* __restrict__ a_src1,
                                              const float* __restrict__ a_dst1,
                                              const int* __restrict__ offs,
                                              const int* __restrict__ csr_src,
                                              unsigned short* __restrict__ agg_hi,
                                              unsigned short* __restrict__ agg_lo){
  __shared__ float s_e[MAXD][HEADS];
  __shared__ int s_src[MAXD];
  __shared__ unsigned s_maxu[HEADS];
  __shared__ float s_sum[HEADS];
  __shared__ float s_inv[HEADS];
  __shared__ float s_ad[HEADS];
  const int n = blockIdx.x, tid = threadIdx.x;
  const int start = offs[n];
  int deg = offs[n+1] - start;
  if (deg > MAXD) deg = MAXD;
  if (tid < HEADS){
    s_maxu[tid] = 0u;
    s_sum[tid] = 0.f;
    s_ad[tid] = a_dst1[n*HEADS + tid];
  }
  for (int i = tid; i < deg; i += 128) s_src[i] = csr_src[start + i];
  __syncthreads();
  const int tot = deg*HEADS;
  for (int i = tid; i < tot; i += 128){
    int e = i >> 3, hh = i & 7;
    float v = a_src1[s_src[e]*HEADS + hh] + s_ad[hh];
    v = (v >= 0.f) ? v : NEG*v;
    s_e[e][hh] = v;
    atomicMax(&s_maxu[hh], f2u(v));
  }
  __syncthreads();
  for (int i = tid; i < tot; i += 128){
    int e = i >> 3, hh = i & 7;
    float v = expf(s_e[e][hh] - u2f(s_maxu[hh]));
    s_e[e][hh] = v;
    atomicAdd(&s_sum[hh], v);
  }
  __syncthreads();
  if (tid < HEADS) s_inv[tid] = 1.f/(s_sum[tid] + 1e-16f);
  __syncthreads();
  for (int i = tid; i < tot; i += 128) s_e[i>>3][i&7] *= s_inv[i&7];
  __syncthreads();
  float acc[HEADS] = {0,0,0,0,0,0,0,0};
  for (int e = 0; e < deg; ++e){
    float xv = x[(size_t)s_src[e]*FIN + tid];
    #pragma unroll
    for (int h = 0; h < HEADS; ++h) acc[h] = fmaf(s_e[e][h], xv, acc[h]);
  }
  #pragma unroll
  for (int h = 0; h < HEADS; ++h){
    float v = acc[h];
    unsigned short hi = bf16_rne(v);
    float hf = __uint_as_float((unsigned)hi << 16);
    unsigned short lo = bf16_rne(v - hf);
    size_t idx = ((size_t)n*HEADS + h)*FIN + tid;
    agg_hi[idx] = hi;
    agg_lo[idx] = lo;
  }
}

// ---------- pure MFMA GEMM: out1 = ELU(agg @ W1 + b1), f32 ----------
// 128x128 tile, 4 waves (2x2), wave tile 64x64, 4x4 16x16x32 bf16 frags.
// bf16x3 split; no LDS, no barriers.
__global__ __launch_bounds__(256) void k_gemm1(const unsigned short* __restrict__ agg_hi,
                                               const unsigned short* __restrict__ agg_lo,
                                               const unsigned short* __restrict__ w1t_hi,
                                               const unsigned short* __restrict__ w1t_lo,
                                               const float* __restrict__ b1,
                                               float* __restrict__ out1){
  const int tid = threadIdx.x;
  const int bx = blockIdx.x;           // 0..15 (head = bx>>1)
  const int by = blockIdx.y;           // 0..78
  const int h  = bx >> 1;
  const int colbase = bx*128;
  const int wave = tid >> 6, lane = tid & 63;
  const int wr = wave >> 1, wc = wave & 1;
  const int nl = lane & 15, g = lane >> 4;

  f32x4 zero4 = {0.f, 0.f, 0.f, 0.f};
  f32x4 acc[4][4];
  #pragma unroll
  for (int fm = 0; fm < 4; ++fm)
    #pragma unroll
    for (int fn = 0; fn < 4; ++fn) acc[fm][fn] = zero4;

  const size_t abase = (((size_t)(by*128 + wr*64 + nl))*HEADS + h)*FIN + g*8;
  const size_t bbase = ((size_t)(colbase + wc*64 + nl))*FIN + g*8;

  #pragma unroll
  for (int kc = 0; kc < 4; ++kc){
    bf16x8 ah[4], al[4], bh[4], bl[4];
    #pragma unroll
    for (int f = 0; f < 4; ++f){
      size_t ao = abase + (size_t)f*16*HEADS*FIN + kc*32;
      size_t bo = bbase + (size_t)f*16*FIN + kc*32;
      ah[f] = *reinterpret_cast<const bf16x8*>(agg_hi + ao);
      al[f] = *reinterpret_cast<const bf16x8*>(agg_lo + ao);
      bh[f] = *reinterpret_cast<const bf16x8*>(w1t_hi + bo);
      bl[f] = *reinterpret_cast<const bf16x8*>(w1t_lo + bo);
    }
    #pragma unroll
    for (int fm = 0; fm < 4; ++fm)
      #pragma unroll
      for (int fn = 0; fn < 4; ++fn){
        acc[fm][fn] = __builtin_amdgcn_mfma_f32_16x16x32_bf16(ah[fm], bh[fn], acc[fm][fn], 0, 0, 0);
        acc[fm][fn] = __builtin_amdgcn_mfma_f32_16x16x32_bf16(ah[fm], bl[fn], acc[fm][fn], 0, 0, 0);
        acc[fm][fn] = __builtin_amdgcn_mfma_f32_16x16x32_bf16(al[fm], bh[fn], acc[fm][fn], 0, 0, 0);
      }
  }

  // D frag: col = fn*16 + nl, row = fm*16 + g*4 + r (within wave 64x64)
  #pragma unroll
  for (int fm = 0; fm < 4; ++fm){
    #pragma unroll
    for (int fn = 0; fn < 4; ++fn){
      int col = colbase + wc*64 + fn*16 + nl;
      float bb = b1[col];
      #pragma unroll
      for (int r = 0; r < 4; ++r){
        int row = by*128 + wr*64 + fm*16 + g*4 + r;
        if (row < N_NODES){
          float v = acc[fm][fn][r] + bb;
          v = (v > 0.f) ? v : (__expf(v) - 1.f);   // fused ELU
          out1[(size_t)row*HC + col] = v;
        }
      }
    }
  }
}

// ---------- layer-2 projection: h2 = out1 @ W2 (+ attention dots) ----------
// 16 nodes per block; thread (ng,nl): node group x 16-lane k-strip.
__global__ __launch_bounds__(256) void k_gemv2(const float* __restrict__ out1,
                                               const float* __restrict__ W2t,
                                               const float* __restrict__ as2,
                                               const float* __restrict__ ad2,
                                               float* __restrict__ h2,
                                               float* __restrict__ a_src2,
                                               float* __restrict__ a_dst2){
  const int tid = threadIdx.x;
  const int nl = tid & 15;
  const int ng = tid >> 4;
  const int n = blockIdx.x*16 + ng;
  float acc[NC];
  #pragma unroll
  for (int j = 0; j < NC; ++j) acc[j] = 0.f;
  const float* row = out1 + (size_t)n*HC;
  for (int i = 0; i < 32; ++i){          // 32 * 16 lanes * 4 = 2048
    int k = i*64 + nl*4;
    float4 v = *reinterpret_cast<const float4*>(row + k);
    #pragma unroll
    for (int j = 0; j < NC; ++j){
      float4 w = *reinterpret_cast<const float4*>(W2t + (size_t)j*HC + k);
      acc[j] += v.x*w.x + v.y*w.y + v.z*w.z + v.w*w.w;
    }
  }
  #pragma unroll
  for (int o = 1; o < 16; o <<= 1){
    #pragma unroll
    for (int j = 0; j < NC; ++j) acc[j] += __shfl_xor(acc[j], o);
  }
  if (nl == 0){
    float ds = 0.f, dd = 0.f;
    #pragma unroll
    for (int j = 0; j < NC; ++j){
      h2[(size_t)n*NC + j] = acc[j];
      ds = fmaf(acc[j], as2[j], ds);
      dd = fmaf(acc[j], ad2[j], dd);
    }
    a_src2[n] = ds;
    a_dst2[n] = dd;
  }
}

// ---------- layer-2 aggregation + sigmoid (wave-parallel alphas) ----------
__global__ __launch_bounds__(64) void k_agg2(const float* __restrict__ h2,
                                             const float* __restrict__ a_src2,
                                             const float* __restrict__ a_dst2,
                                             const int* __restrict__ offs,
                                             const int* __restrict__ csr_src,
                                             const float* __restrict__ b2,
                                             float* __restrict__ out){
  __shared__ float s_al[MAXD2];
  __shared__ int s_sc[MAXD2];
  const int n = blockIdx.x, lane = threadIdx.x;
  const int start = offs[n];
  int deg = offs[n+1] - start;
  if (deg > MAXD2) deg = MAXD2;
  const float ad = a_dst2[n];
  float e = -INFINITY;
  if (lane < deg){
    int src = csr_src[start + lane];
    s_sc[lane] = src;
    e = a_src2[src] + ad;
    e = (e >= 0.f) ? e : NEG*e;
  }
  float m = e;
  #pragma unroll
  for (int o = 1; o < 64; o <<= 1) m = fmaxf(m, __shfl_xor(m, o));
  float ex = (lane < deg) ? expf(e - m) : 0.f;
  float s = ex;
  #pragma unroll
  for (int o = 1; o < 64; o <<= 1) s += __shfl_xor(s, o);
  if (lane < deg) s_al[lane] = ex / (s + 1e-16f);
  __syncthreads();
  if (lane < NC){
    float acc = 0.f;
    for (int i = 0; i < deg; ++i)
      acc = fmaf(s_al[i], h2[(size_t)s_sc[i]*NC + lane], acc);
    float v = acc + b2[lane];
    out[n*NC + lane] = 1.f/(1.f + expf(-v));
  }
}

// ---------- launch ----------
extern "C" void kernel_launch(void* const* d_in, const int* in_sizes, int n_in,
                              void* d_out, int out_size, void* d_ws, size_t ws_size,
                              hipStream_t stream){
  const float* x   = (const float*)d_in[0];
  const int*   ei  = (const int*)  d_in[1];
  const float* W1  = (const float*)d_in[2];
  const float* as1 = (const float*)d_in[3];
  const float* ad1 = (const float*)d_in[4];
  const float* b1  = (const float*)d_in[5];
  const float* W2  = (const float*)d_in[6];
  const float* as2 = (const float*)d_in[7];
  const float* ad2 = (const float*)d_in[8];
  const float* b2  = (const float*)d_in[9];
  float* out = (float*)d_out;

  char* ws = (char*)d_ws;
  size_t off = 0;
  auto alloc = [&](size_t bytes) -> void* {
    void* p = ws + off;
    off += (bytes + 255) & ~(size_t)255;
    return p;
  };
  float* out1    = (float*)alloc((size_t)N_NODES*HC*4);                        // 81.9 MB
  unsigned short* agg_hi = (unsigned short*)alloc((size_t)N_PAD*HEADS*FIN*2);  // 20.7 MB
  unsigned short* agg_lo = (unsigned short*)alloc((size_t)N_PAD*HEADS*FIN*2);  // 20.7 MB
  unsigned short* w1t_hi = (unsigned short*)alloc((size_t)HC*FIN*2);
  unsigned short* w1t_lo = (unsigned short*)alloc((size_t)HC*FIN*2);
  float* W2t     = (float*)alloc((size_t)NC*HC*4);
  float* vv      = (float*)alloc((size_t)FIN*16*4);
  float* a_src1  = (float*)alloc((size_t)N_NODES*HEADS*4);
  float* a_dst1  = (float*)alloc((size_t)N_NODES*HEADS*4);
  float* h2      = (float*)alloc((size_t)N_NODES*NC*4);
  float* a_src2  = (float*)alloc((size_t)N_NODES*4);
  float* a_dst2  = (float*)alloc((size_t)N_NODES*4);
  int*   deg     = (int*)alloc((size_t)N_NODES*4);
  int*   offs    = (int*)alloc((size_t)(N_NODES+1)*4);
  int*   cursor  = (int*)alloc((size_t)N_NODES*4);
  int*   esrc    = (int*)alloc((size_t)E_TOT*4);
  int*   edst    = (int*)alloc((size_t)E_TOT*4);
  int*   csr_src = (int*)alloc((size_t)E_TOT*4);
  int*   flag    = (int*)alloc(4);
  (void)ws_size; (void)in_sizes; (void)n_in; (void)out_size;

  k_init   <<<40, 256, 0, stream>>>(ei, flag, deg, cursor);
  k_convert<<<(E_TOT + 255)/256, 256, 0, stream>>>(ei, flag, esrc, edst, deg);
  k_prepw  <<<(HC*FIN)/256, 256, 0, stream>>>(W1, as1, ad1, W2, w1t_hi, w1t_lo, W2t, vv);
  k_attdot <<<N_NODES/4, 256, 0, stream>>>(x, vv, a_src1, a_dst1);
  k_scan   <<<1, 1024, 0, stream>>>(deg, offs);
  k_scatter<<<(E_TOT + 255)/256, 256, 0, stream>>>(esrc, edst, offs, cursor, csr_src);
  k_aggx   <<<N_NODES, 128, 0, stream>>>(x, a_src1, a_dst1, offs, csr_src, agg_hi, agg_lo);
  k_gemm1  <<<dim3(16, N_PAD/128), 256, 0, stream>>>(agg_hi, agg_lo, w1t_hi, w1t_lo, b1, out1);
  k_gemv2  <<<N_NODES/16, 256, 0, stream>>>(out1, W2t, as2, ad2, h2, a_src2, a_dst2);
  k_agg2   <<<N_NODES, 64, 0, stream>>>(h2, a_src2, a_dst2, offs, csr_src, b2, out);
}